// Round 1
// baseline (167.918 us; speedup 1.0000x reference)
//
#include <hip/hip_runtime.h>
#include <hip/hip_bf16.h>
#include <math.h>

#define Bq   8
#define DINq 256
#define Nq   2048

typedef __attribute__((ext_vector_type(8))) short bf16x8v;
typedef __attribute__((ext_vector_type(4))) float f32x4v;

__device__ __forceinline__ unsigned short f2bf(float f) {
  union { float f; unsigned u; } v; v.f = f;
  unsigned r = v.u + 0x7fffu + ((v.u >> 16) & 1u);
  return (unsigned short)(r >> 16);
}
__device__ __forceinline__ float bf2f(unsigned short h) {
  union { unsigned u; float f; } v; v.u = ((unsigned)h) << 16;
  return v.f;
}

__device__ __forceinline__ void gld_lds16(const void* g, void* l) {
  __builtin_amdgcn_global_load_lds(
      (const __attribute__((address_space(1))) unsigned int*)g,
      (__attribute__((address_space(3))) unsigned int*)l, 16, 0, 0);
}

// ---- w123[k] = (W^T a1)[k], (W^T a2)[k], (W^T a3)[k] ----
__global__ void k_prep(const float* __restrict__ W, const float* __restrict__ a,
                       float* __restrict__ w123) {
  int k = threadIdx.x;
  float s1 = 0.f, s2 = 0.f, s3 = 0.f;
  for (int d = 0; d < DINq; ++d) {
    float w = W[d * DINq + k];
    s1 += w * a[d];
    s2 += w * a[DINq + d];
    s3 += w * a[2 * DINq + d];
  }
  w123[k] = s1; w123[DINq + k] = s2; w123[2 * DINq + k] = s3;
}

// ---- WT[k][d] = W[d][k] ----
__global__ void k_transposeW(const float* __restrict__ W, float* __restrict__ WT) {
  int d = blockIdx.x, k = threadIdx.x;
  WT[(size_t)k * DINq + d] = W[(size_t)d * DINq + k];
}

// ---- t, si, sb per (b,i): dot of x column with w123 vectors ----
__global__ void k_tsisb(const float* __restrict__ x, const float* __restrict__ w123,
                        float* __restrict__ tA, float* __restrict__ siA,
                        float* __restrict__ sbA) {
  int b = blockIdx.y;
  int il = threadIdx.x & 63;
  int i = blockIdx.x * 64 + il;
  int ks = (threadIdx.x >> 6) * 64;
  float a1 = 0.f, a2 = 0.f, a3 = 0.f;
  for (int k = ks; k < ks + 64; ++k) {
    float xv = x[((size_t)b * DINq + k) * Nq + i];
    a1 += xv * w123[k];
    a2 += xv * w123[DINq + k];
    a3 += xv * w123[2 * DINq + k];
  }
  __shared__ float r1[256], r2[256], r3[256];
  r1[threadIdx.x] = a1; r2[threadIdx.x] = a2; r3[threadIdx.x] = a3;
  __syncthreads();
  if (threadIdx.x < 64) {
    int l = threadIdx.x;
    float v1 = r1[l] + r1[64 + l] + r1[128 + l] + r1[192 + l];
    float v2 = r2[l] + r2[64 + l] + r2[128 + l] + r2[192 + l];
    float v3 = r3[l] + r3[64 + l] + r3[128 + l] + r3[192 + l];
    int ii = blockIdx.x * 64 + l;
    siA[(size_t)b * Nq + ii] = v1;
    sbA[(size_t)b * Nq + ii] = v2;
    tA[(size_t)b * Nq + ii] = v3;
  }
}

// ---- h[b,i,d] (fp32) and X^T[(b,d)][i] = t[b,i]*h[b,i,d] split hi/lo bf16 ----
__global__ void k_hX(const float* __restrict__ x, const float* __restrict__ WT,
                     const float* __restrict__ tA, float* __restrict__ h,
                     unsigned short* __restrict__ Xhi, unsigned short* __restrict__ Xlo) {
  __shared__ float xs[64][64];
  __shared__ float ws[64][128];
  const int tid = threadIdx.x;
  const int iq = tid & 15;      // 4 i's each
  const int dg = tid >> 4;      // 16 groups of 8 d's
  const int i0 = blockIdx.x * 64;
  const int dh = blockIdx.y;    // d half: 0 or 1
  const int b = blockIdx.z;

  float acc[4][8];
#pragma unroll
  for (int aa = 0; aa < 4; ++aa)
#pragma unroll
    for (int cc = 0; cc < 8; ++cc) acc[aa][cc] = 0.f;

  for (int kc = 0; kc < 4; ++kc) {
#pragma unroll
    for (int n = 0; n < 16; ++n) {
      int idx = n * 256 + tid;
      int kk = idx >> 6, ii = idx & 63;
      xs[kk][ii] = x[((size_t)b * DINq + kc * 64 + kk) * Nq + i0 + ii];
    }
#pragma unroll
    for (int n = 0; n < 8; ++n) {
      int idx = n * 256 + tid;
      int kk = idx >> 5, c4 = (idx & 31) * 4;
      *(f32x4v*)&ws[kk][c4] =
          *(const f32x4v*)&WT[(size_t)(kc * 64 + kk) * DINq + dh * 128 + c4];
    }
    __syncthreads();
#pragma unroll 4
    for (int kk = 0; kk < 64; ++kk) {
      f32x4v xv = *(const f32x4v*)&xs[kk][iq * 4];
      f32x4v w0 = *(const f32x4v*)&ws[kk][dg * 8];
      f32x4v w1 = *(const f32x4v*)&ws[kk][dg * 8 + 4];
#pragma unroll
      for (int aa = 0; aa < 4; ++aa) {
#pragma unroll
        for (int cc = 0; cc < 4; ++cc) {
          acc[aa][cc]     += xv[aa] * w0[cc];
          acc[aa][cc + 4] += xv[aa] * w1[cc];
        }
      }
    }
    __syncthreads();
  }

  const int ib = i0 + iq * 4;
  float tv[4];
#pragma unroll
  for (int aa = 0; aa < 4; ++aa) tv[aa] = tA[(size_t)b * Nq + ib + aa];

#pragma unroll
  for (int aa = 0; aa < 4; ++aa) {
    size_t hoff = ((size_t)b * Nq + ib + aa) * DINq + dh * 128 + dg * 8;
    f32x4v h0, h1;
#pragma unroll
    for (int cc = 0; cc < 4; ++cc) { h0[cc] = acc[aa][cc]; h1[cc] = acc[aa][cc + 4]; }
    *(f32x4v*)&h[hoff] = h0;
    *(f32x4v*)&h[hoff + 4] = h1;
  }
#pragma unroll
  for (int cc = 0; cc < 8; ++cc) {
    int d = dh * 128 + dg * 8 + cc;
    unsigned short hv[4], lv[4];
#pragma unroll
    for (int aa = 0; aa < 4; ++aa) {
      float Xv = tv[aa] * acc[aa][cc];
      unsigned short hs = f2bf(Xv);
      hv[aa] = hs;
      lv[aa] = f2bf(Xv - bf2f(hs));
    }
    size_t xoff = ((size_t)b * DINq + d) * Nq + ib;
    *(ushort4*)&Xhi[xoff] = make_ushort4(hv[0], hv[1], hv[2], hv[3]);
    *(ushort4*)&Xlo[xoff] = make_ushort4(lv[0], lv[1], lv[2], lv[3]);
  }
}

// ---- Mb[i][j] = (adj!=0 && i!=j) ? 1.0bf16 : 0 ----
__global__ void k_mask(const int* __restrict__ adj, unsigned short* __restrict__ Mb) {
  size_t idx = ((size_t)blockIdx.x * 256 + threadIdx.x) * 8;
  int i = (int)(idx >> 11);
  int j0 = (int)(idx & (Nq - 1));
  const int4* ap = (const int4*)&adj[idx];
  int4 a0 = ap[0], a1 = ap[1];
  int av[8] = {a0.x, a0.y, a0.z, a0.w, a1.x, a1.y, a1.z, a1.w};
  unsigned short v[8];
#pragma unroll
  for (int q = 0; q < 8; ++q)
    v[q] = (av[q] != 0 && (j0 + q) != i) ? (unsigned short)0x3F80 : (unsigned short)0;
  ushort4* mp = (ushort4*)&Mb[idx];
  mp[0] = make_ushort4(v[0], v[1], v[2], v[3]);
  mp[1] = make_ushort4(v[4], v[5], v[6], v[7]);
}

// ---- G = Mb @ (Xhi + Xlo)^T : 2048x2048x2048, 128x128 tiles, m97-style ----
__global__ __launch_bounds__(256) void k_gemm(const unsigned short* __restrict__ Mb,
                                              const unsigned short* __restrict__ Xhi,
                                              const unsigned short* __restrict__ Xlo,
                                              float* __restrict__ G) {
  __shared__ unsigned short As[128 * 64];
  __shared__ unsigned short Bh[128 * 64];
  __shared__ unsigned short Bl[128 * 64];
  const int tid = threadIdx.x;
  const int lane = tid & 63;
  const int wave = tid >> 6;
  const int wr = wave >> 1, wc = wave & 1;
  const int i0 = blockIdx.y * 128, c0 = blockIdx.x * 128;
  const int sr = tid >> 3, sc = (tid & 7) * 8;
  const int r15 = lane & 15, kg = lane >> 4;

  f32x4v acc[4][4];
#pragma unroll
  for (int m = 0; m < 4; ++m)
#pragma unroll
    for (int n = 0; n < 4; ++n) acc[m][n] = (f32x4v)0.f;

  for (int k0 = 0; k0 < Nq; k0 += 64) {
#pragma unroll
    for (int n = 0; n < 4; ++n) {
      int row = n * 32 + sr;
      gld_lds16(&Mb[(size_t)(i0 + row) * Nq + k0 + sc], &As[row * 64 + sc]);
      gld_lds16(&Xhi[(size_t)(c0 + row) * Nq + k0 + sc], &Bh[row * 64 + sc]);
      gld_lds16(&Xlo[(size_t)(c0 + row) * Nq + k0 + sc], &Bl[row * 64 + sc]);
    }
    __syncthreads();
#pragma unroll
    for (int kk = 0; kk < 2; ++kk) {
      const int ko = kk * 32 + kg * 8;
      bf16x8v af[4], bhf[4], blf[4];
#pragma unroll
      for (int m = 0; m < 4; ++m)
        af[m] = *(const bf16x8v*)&As[(wr * 64 + m * 16 + r15) * 64 + ko];
#pragma unroll
      for (int n = 0; n < 4; ++n) {
        bhf[n] = *(const bf16x8v*)&Bh[(wc * 64 + n * 16 + r15) * 64 + ko];
        blf[n] = *(const bf16x8v*)&Bl[(wc * 64 + n * 16 + r15) * 64 + ko];
      }
#pragma unroll
      for (int m = 0; m < 4; ++m)
#pragma unroll
        for (int n = 0; n < 4; ++n) {
          acc[m][n] = __builtin_amdgcn_mfma_f32_16x16x32_bf16(af[m], bhf[n], acc[m][n], 0, 0, 0);
          acc[m][n] = __builtin_amdgcn_mfma_f32_16x16x32_bf16(af[m], blf[n], acc[m][n], 0, 0, 0);
        }
    }
    __syncthreads();
  }
  const int re = (lane >> 4) * 4, ce = lane & 15;
#pragma unroll
  for (int m = 0; m < 4; ++m)
#pragma unroll
    for (int n = 0; n < 4; ++n) {
      size_t base = (size_t)(i0 + wr * 64 + m * 16 + re) * Nq + c0 + wc * 64 + n * 16 + ce;
#pragma unroll
      for (int r = 0; r < 4; ++r) G[base + (size_t)r * Nq] = acc[m][n][r];
    }
}

// ---- sjv[b,i] = sb[b,i] + dot(G[i, b*256: (b+1)*256], h[b,i,:]) ----
__global__ void k_sjv(const float* __restrict__ G, const float* __restrict__ h,
                      const float* __restrict__ sbA, float* __restrict__ sjvA) {
  int gw = blockIdx.x * 4 + (threadIdx.x >> 6);
  int lane = threadIdx.x & 63;
  int b = gw >> 11, i = gw & (Nq - 1);
  f32x4v g = *(const f32x4v*)&G[(size_t)i * Nq + b * DINq + lane * 4];
  f32x4v hv = *(const f32x4v*)&h[((size_t)b * Nq + i) * DINq + lane * 4];
  float s = g[0] * hv[0] + g[1] * hv[1] + g[2] * hv[2] + g[3] * hv[3];
#pragma unroll
  for (int o = 32; o >= 1; o >>= 1) s += __shfl_xor(s, o, 64);
  if (lane == 0) sjvA[(size_t)b * Nq + i] = sbA[(size_t)b * Nq + i] + s;
}

// ---- out[b,i,:] = softmax_j( mask(adj, lrelu(si[b,i] + sjv[b,j])) ) ----
__global__ void k_softmax(const int* __restrict__ adj, const float* __restrict__ siA,
                          const float* __restrict__ sjvA, float* __restrict__ out) {
  const int b = blockIdx.y, i = blockIdx.x, tid = threadIdx.x;
  const float siv = siA[(size_t)b * Nq + i];
  const int* arow = adj + (size_t)i * Nq;
  const float* sjb = sjvA + (size_t)b * Nq;
  float sc[8];
  float mx = -3.0e38f;
#pragma unroll
  for (int s = 0; s < 8; ++s) {
    int j = s * 256 + tid;
    float v = siv + sjb[j];
    v = v > 0.f ? v : 0.2f * v;
    v = (arow[j] != 0) ? v : -9.0e15f;
    sc[s] = v;
    mx = fmaxf(mx, v);
  }
#pragma unroll
  for (int o = 32; o >= 1; o >>= 1) mx = fmaxf(mx, __shfl_xor(mx, o, 64));
  __shared__ float redm[4], reds[4];
  const int wave = tid >> 6, lane = tid & 63;
  if (lane == 0) redm[wave] = mx;
  __syncthreads();
  mx = fmaxf(fmaxf(redm[0], redm[1]), fmaxf(redm[2], redm[3]));
  float sum = 0.f, ex[8];
#pragma unroll
  for (int s = 0; s < 8; ++s) { ex[s] = expf(sc[s] - mx); sum += ex[s]; }
#pragma unroll
  for (int o = 32; o >= 1; o >>= 1) sum += __shfl_xor(sum, o, 64);
  if (lane == 0) reds[wave] = sum;
  __syncthreads();
  sum = reds[0] + reds[1] + reds[2] + reds[3];
  float inv = 1.f / sum;
  float* orow = out + ((size_t)b * Nq + i) * Nq;
#pragma unroll
  for (int s = 0; s < 8; ++s) orow[s * 256 + tid] = ex[s] * inv;
}

extern "C" void kernel_launch(void* const* d_in, const int* in_sizes, int n_in,
                              void* d_out, int out_size, void* d_ws, size_t ws_size,
                              hipStream_t stream) {
  const float* x = (const float*)d_in[0];
  const int* adj = (const int*)d_in[1];
  const float* W = (const float*)d_in[2];
  const float* a = (const float*)d_in[3];
  float* out = (float*)d_out;

  char* ws = (char*)d_ws;
  size_t off = 0;
  auto alloc = [&](size_t bytes) -> void* {
    void* p = ws + off;
    off += (bytes + 255) & ~(size_t)255;
    return p;
  };
  float* w123 = (float*)alloc(3 * DINq * sizeof(float));
  float* WT = (float*)alloc((size_t)DINq * DINq * sizeof(float));
  float* tA = (float*)alloc((size_t)Bq * Nq * sizeof(float));
  float* siA = (float*)alloc((size_t)Bq * Nq * sizeof(float));
  float* sbA = (float*)alloc((size_t)Bq * Nq * sizeof(float));
  float* sjvA = (float*)alloc((size_t)Bq * Nq * sizeof(float));
  float* h = (float*)alloc((size_t)Bq * Nq * DINq * sizeof(float));
  unsigned short* Xhi = (unsigned short*)alloc((size_t)Nq * Nq * 2);
  unsigned short* Xlo = (unsigned short*)alloc((size_t)Nq * Nq * 2);
  unsigned short* Mb = (unsigned short*)alloc((size_t)Nq * Nq * 2);
  float* G = (float*)alloc((size_t)Nq * Nq * sizeof(float));

  k_prep<<<dim3(1), dim3(256), 0, stream>>>(W, a, w123);
  k_transposeW<<<dim3(DINq), dim3(DINq), 0, stream>>>(W, WT);
  k_tsisb<<<dim3(Nq / 64, Bq), dim3(256), 0, stream>>>(x, w123, tA, siA, sbA);
  k_hX<<<dim3(Nq / 64, 2, Bq), dim3(256), 0, stream>>>(x, WT, tA, h, Xhi, Xlo);
  k_mask<<<dim3(Nq * Nq / (256 * 8)), dim3(256), 0, stream>>>(adj, Mb);
  k_gemm<<<dim3(16, 16), dim3(256), 0, stream>>>(Mb, Xhi, Xlo, G);
  k_sjv<<<dim3(Bq * Nq / 4), dim3(256), 0, stream>>>(G, h, sbA, sjvA);
  k_softmax<<<dim3(Nq, Bq), dim3(256), 0, stream>>>(adj, siA, sjvA, out);
}

// Round 2
// 162.999 us; speedup vs baseline: 1.0302x; 1.0302x over previous
//
#include <hip/hip_runtime.h>
#include <hip/hip_bf16.h>
#include <math.h>

#define Bq   8
#define DINq 256
#define Nq   2048

typedef __attribute__((ext_vector_type(8))) short bf16x8v;
typedef __attribute__((ext_vector_type(4))) float f32x4v;

__device__ __forceinline__ unsigned short f2bf(float f) {
  union { float f; unsigned u; } v; v.f = f;
  unsigned r = v.u + 0x7fffu + ((v.u >> 16) & 1u);
  return (unsigned short)(r >> 16);
}
__device__ __forceinline__ float bf2f(unsigned short h) {
  union { unsigned u; float f; } v; v.u = ((unsigned)h) << 16;
  return v.f;
}

__device__ __forceinline__ void gld_lds16(const void* g, void* l) {
  __builtin_amdgcn_global_load_lds(
      (const __attribute__((address_space(1))) unsigned int*)g,
      (__attribute__((address_space(3))) unsigned int*)l, 16, 0, 0);
}

// ---- w123[k] = (W^T a1)[k], (W^T a2)[k], (W^T a3)[k] ----
__global__ void k_prep(const float* __restrict__ W, const float* __restrict__ a,
                       float* __restrict__ w123) {
  int k = threadIdx.x;
  float s1 = 0.f, s2 = 0.f, s3 = 0.f;
  for (int d = 0; d < DINq; ++d) {
    float w = W[d * DINq + k];
    s1 += w * a[d];
    s2 += w * a[DINq + d];
    s3 += w * a[2 * DINq + d];
  }
  w123[k] = s1; w123[DINq + k] = s2; w123[2 * DINq + k] = s3;
}

// ---- WT[k][d] = W[d][k] ----
__global__ void k_transposeW(const float* __restrict__ W, float* __restrict__ WT) {
  int d = blockIdx.x, k = threadIdx.x;
  WT[(size_t)k * DINq + d] = W[(size_t)d * DINq + k];
}

// ---- t, si, sb per (b,i): dot of x column with w123 vectors ----
__global__ void k_tsisb(const float* __restrict__ x, const float* __restrict__ w123,
                        float* __restrict__ tA, float* __restrict__ siA,
                        float* __restrict__ sbA) {
  int b = blockIdx.y;
  int il = threadIdx.x & 63;
  int i = blockIdx.x * 64 + il;
  int ks = (threadIdx.x >> 6) * 64;
  float a1 = 0.f, a2 = 0.f, a3 = 0.f;
  for (int k = ks; k < ks + 64; ++k) {
    float xv = x[((size_t)b * DINq + k) * Nq + i];
    a1 += xv * w123[k];
    a2 += xv * w123[DINq + k];
    a3 += xv * w123[2 * DINq + k];
  }
  __shared__ float r1[256], r2[256], r3[256];
  r1[threadIdx.x] = a1; r2[threadIdx.x] = a2; r3[threadIdx.x] = a3;
  __syncthreads();
  if (threadIdx.x < 64) {
    int l = threadIdx.x;
    float v1 = r1[l] + r1[64 + l] + r1[128 + l] + r1[192 + l];
    float v2 = r2[l] + r2[64 + l] + r2[128 + l] + r2[192 + l];
    float v3 = r3[l] + r3[64 + l] + r3[128 + l] + r3[192 + l];
    int ii = blockIdx.x * 64 + l;
    siA[(size_t)b * Nq + ii] = v1;
    sbA[(size_t)b * Nq + ii] = v2;
    tA[(size_t)b * Nq + ii] = v3;
  }
}

// ---- h[b,i,d] (fp32) and X^T[(b,d)][i] = t[b,i]*h[b,i,d] split hi/lo bf16 ----
__global__ void k_hX(const float* __restrict__ x, const float* __restrict__ WT,
                     const float* __restrict__ tA, float* __restrict__ h,
                     unsigned short* __restrict__ Xhi, unsigned short* __restrict__ Xlo) {
  __shared__ float xs[64][64];
  __shared__ float ws[64][128];
  const int tid = threadIdx.x;
  const int iq = tid & 15;      // 4 i's each
  const int dg = tid >> 4;      // 16 groups of 8 d's
  const int i0 = blockIdx.x * 64;
  const int dh = blockIdx.y;    // d half: 0 or 1
  const int b = blockIdx.z;

  float acc[4][8];
#pragma unroll
  for (int aa = 0; aa < 4; ++aa)
#pragma unroll
    for (int cc = 0; cc < 8; ++cc) acc[aa][cc] = 0.f;

  for (int kc = 0; kc < 4; ++kc) {
#pragma unroll
    for (int n = 0; n < 16; ++n) {
      int idx = n * 256 + tid;
      int kk = idx >> 6, ii = idx & 63;
      xs[kk][ii] = x[((size_t)b * DINq + kc * 64 + kk) * Nq + i0 + ii];
    }
#pragma unroll
    for (int n = 0; n < 8; ++n) {
      int idx = n * 256 + tid;
      int kk = idx >> 5, c4 = (idx & 31) * 4;
      *(f32x4v*)&ws[kk][c4] =
          *(const f32x4v*)&WT[(size_t)(kc * 64 + kk) * DINq + dh * 128 + c4];
    }
    __syncthreads();
#pragma unroll 4
    for (int kk = 0; kk < 64; ++kk) {
      f32x4v xv = *(const f32x4v*)&xs[kk][iq * 4];
      f32x4v w0 = *(const f32x4v*)&ws[kk][dg * 8];
      f32x4v w1 = *(const f32x4v*)&ws[kk][dg * 8 + 4];
#pragma unroll
      for (int aa = 0; aa < 4; ++aa) {
#pragma unroll
        for (int cc = 0; cc < 4; ++cc) {
          acc[aa][cc]     += xv[aa] * w0[cc];
          acc[aa][cc + 4] += xv[aa] * w1[cc];
        }
      }
    }
    __syncthreads();
  }

  const int ib = i0 + iq * 4;
  float tv[4];
#pragma unroll
  for (int aa = 0; aa < 4; ++aa) tv[aa] = tA[(size_t)b * Nq + ib + aa];

#pragma unroll
  for (int aa = 0; aa < 4; ++aa) {
    size_t hoff = ((size_t)b * Nq + ib + aa) * DINq + dh * 128 + dg * 8;
    f32x4v h0, h1;
#pragma unroll
    for (int cc = 0; cc < 4; ++cc) { h0[cc] = acc[aa][cc]; h1[cc] = acc[aa][cc + 4]; }
    *(f32x4v*)&h[hoff] = h0;
    *(f32x4v*)&h[hoff + 4] = h1;
  }
#pragma unroll
  for (int cc = 0; cc < 8; ++cc) {
    int d = dh * 128 + dg * 8 + cc;
    unsigned short hv[4], lv[4];
#pragma unroll
    for (int aa = 0; aa < 4; ++aa) {
      float Xv = tv[aa] * acc[aa][cc];
      unsigned short hs = f2bf(Xv);
      hv[aa] = hs;
      lv[aa] = f2bf(Xv - bf2f(hs));
    }
    size_t xoff = ((size_t)b * DINq + d) * Nq + ib;
    *(ushort4*)&Xhi[xoff] = make_ushort4(hv[0], hv[1], hv[2], hv[3]);
    *(ushort4*)&Xlo[xoff] = make_ushort4(lv[0], lv[1], lv[2], lv[3]);
  }
}

// ---- Mb[i][j] = (adj!=0 && i!=j) ? 1.0bf16 : 0 ----
__global__ void k_mask(const int* __restrict__ adj, unsigned short* __restrict__ Mb) {
  size_t idx = ((size_t)blockIdx.x * 256 + threadIdx.x) * 8;
  int i = (int)(idx >> 11);
  int j0 = (int)(idx & (Nq - 1));
  const int4* ap = (const int4*)&adj[idx];
  int4 a0 = ap[0], a1 = ap[1];
  int av[8] = {a0.x, a0.y, a0.z, a0.w, a1.x, a1.y, a1.z, a1.w};
  unsigned short v[8];
#pragma unroll
  for (int q = 0; q < 8; ++q)
    v[q] = (av[q] != 0 && (j0 + q) != i) ? (unsigned short)0x3F80 : (unsigned short)0;
  ushort4* mp = (ushort4*)&Mb[idx];
  mp[0] = make_ushort4(v[0], v[1], v[2], v[3]);
  mp[1] = make_ushort4(v[4], v[5], v[6], v[7]);
}

// ---- z-split GEMM: for z in {hi,lo}: Gz = Mb @ Xz^T (128x128 tile), fused
//      epilogue reduces sjv partial = sum_d h[b,i,d]*Gz[i,(b,d)] into sjp slices ----
__global__ __launch_bounds__(256) void k_gemm(const unsigned short* __restrict__ Mb,
                                              const unsigned short* __restrict__ Xhi,
                                              const unsigned short* __restrict__ Xlo,
                                              const float* __restrict__ h,
                                              float* __restrict__ sjp) {
  __shared__ unsigned short As[2][128 * 64];
  __shared__ unsigned short Bs[2][128 * 64];
  const int tid = threadIdx.x;
  const int lane = tid & 63;
  const int wave = tid >> 6;
  const int wr = wave >> 1, wc = wave & 1;
  const int i0 = blockIdx.y * 128, c0 = blockIdx.x * 128;
  const int z = blockIdx.z;
  const unsigned short* __restrict__ Xp = z ? Xlo : Xhi;
  const int srow = tid >> 3;           // 0..31
  const int scol = (tid & 7) * 8;      // bf16 elems, 16B chunks
  const int r15 = lane & 15, kg = lane >> 4;

  f32x4v acc[4][4];
#pragma unroll
  for (int m = 0; m < 4; ++m)
#pragma unroll
    for (int n = 0; n < 4; ++n) acc[m][n] = (f32x4v)0.f;

  auto STAGE = [&](int buf, int t) {
    const int k0 = t * 64;
#pragma unroll
    for (int n = 0; n < 4; ++n) {
      int row = n * 32 + srow;
      gld_lds16(&Mb[(size_t)(i0 + row) * Nq + k0 + scol], &As[buf][row * 64 + scol]);
      gld_lds16(&Xp[(size_t)(c0 + row) * Nq + k0 + scol], &Bs[buf][row * 64 + scol]);
    }
  };

  STAGE(0, 0);
  __syncthreads();
  int cur = 0;
  for (int t = 0; t < Nq / 64; ++t) {
    if (t + 1 < Nq / 64) STAGE(cur ^ 1, t + 1);
#pragma unroll
    for (int kk = 0; kk < 2; ++kk) {
      const int ko = kk * 32 + kg * 8;
      bf16x8v af[4], bf[4];
#pragma unroll
      for (int m = 0; m < 4; ++m)
        af[m] = *(const bf16x8v*)&As[cur][(wr * 64 + m * 16 + r15) * 64 + ko];
#pragma unroll
      for (int n = 0; n < 4; ++n)
        bf[n] = *(const bf16x8v*)&Bs[cur][(wc * 64 + n * 16 + r15) * 64 + ko];
#pragma unroll
      for (int m = 0; m < 4; ++m)
#pragma unroll
        for (int n = 0; n < 4; ++n)
          acc[m][n] = __builtin_amdgcn_mfma_f32_16x16x32_bf16(af[m], bf[n], acc[m][n], 0, 0, 0);
    }
    __syncthreads();
    cur ^= 1;
  }

  // Fused epilogue: partial[b, i] += sum over this block's 64-col (per wave) slice
  // of h[b, i, d] * acc. Cols c = c0 + wc*64 + n*16 + ce -> b = c>>8, d = c&255.
  const int b = c0 >> 8;
  const int d0 = (c0 & 255) + wc * 64;
  const int re = (lane >> 4) * 4, ce = lane & 15;
  float s[4][4];
#pragma unroll
  for (int m = 0; m < 4; ++m)
#pragma unroll
    for (int r = 0; r < 4; ++r) s[m][r] = 0.f;
#pragma unroll
  for (int m = 0; m < 4; ++m) {
#pragma unroll
    for (int n = 0; n < 4; ++n) {
#pragma unroll
      for (int r = 0; r < 4; ++r) {
        float hv = h[((size_t)b * Nq + i0 + wr * 64 + m * 16 + re + r) * DINq + d0 + n * 16 + ce];
        s[m][r] += acc[m][n][r] * hv;
      }
    }
  }
#pragma unroll
  for (int o = 1; o < 16; o <<= 1) {
#pragma unroll
    for (int m = 0; m < 4; ++m)
#pragma unroll
      for (int r = 0; r < 4; ++r) s[m][r] += __shfl_xor(s[m][r], o, 64);
  }
  if (ce == 0) {
    const int slice = z * 4 + (blockIdx.x & 1) * 2 + wc;
    float* sp = sjp + ((size_t)slice * Bq + b) * Nq;
#pragma unroll
    for (int m = 0; m < 4; ++m)
#pragma unroll
      for (int r = 0; r < 4; ++r)
        sp[i0 + wr * 64 + m * 16 + re + r] = s[m][r];
  }
}

// ---- sjv[b,i] = sb[b,i] + sum of 8 partial slices ----
__global__ void k_sjsum(const float* __restrict__ sbA, const float* __restrict__ sjp,
                        float* __restrict__ sjvA) {
  int idx = blockIdx.x * 256 + threadIdx.x;
  float s = sbA[idx];
#pragma unroll
  for (int sl = 0; sl < 8; ++sl) s += sjp[(size_t)sl * Bq * Nq + idx];
  sjvA[idx] = s;
}

// ---- out[b,i,:] = softmax_j( mask(adj, lrelu(si[b,i] + sjv[b,j])) ) ----
__global__ void k_softmax(const int* __restrict__ adj, const float* __restrict__ siA,
                          const float* __restrict__ sjvA, float* __restrict__ out) {
  const int b = blockIdx.y, i = blockIdx.x, tid = threadIdx.x;
  const float siv = siA[(size_t)b * Nq + i];
  const int* arow = adj + (size_t)i * Nq;
  const float* sjb = sjvA + (size_t)b * Nq;
  float sc[8];
  float mx = -3.0e38f;
#pragma unroll
  for (int s = 0; s < 8; ++s) {
    int j = s * 256 + tid;
    float v = siv + sjb[j];
    v = v > 0.f ? v : 0.2f * v;
    v = (arow[j] != 0) ? v : -9.0e15f;
    sc[s] = v;
    mx = fmaxf(mx, v);
  }
#pragma unroll
  for (int o = 32; o >= 1; o >>= 1) mx = fmaxf(mx, __shfl_xor(mx, o, 64));
  __shared__ float redm[4], reds[4];
  const int wave = tid >> 6, lane = tid & 63;
  if (lane == 0) redm[wave] = mx;
  __syncthreads();
  mx = fmaxf(fmaxf(redm[0], redm[1]), fmaxf(redm[2], redm[3]));
  float sum = 0.f, ex[8];
#pragma unroll
  for (int s = 0; s < 8; ++s) { ex[s] = expf(sc[s] - mx); sum += ex[s]; }
#pragma unroll
  for (int o = 32; o >= 1; o >>= 1) sum += __shfl_xor(sum, o, 64);
  if (lane == 0) reds[wave] = sum;
  __syncthreads();
  sum = reds[0] + reds[1] + reds[2] + reds[3];
  float inv = 1.f / sum;
  float* orow = out + ((size_t)b * Nq + i) * Nq;
#pragma unroll
  for (int s = 0; s < 8; ++s) orow[s * 256 + tid] = ex[s] * inv;
}

extern "C" void kernel_launch(void* const* d_in, const int* in_sizes, int n_in,
                              void* d_out, int out_size, void* d_ws, size_t ws_size,
                              hipStream_t stream) {
  const float* x = (const float*)d_in[0];
  const int* adj = (const int*)d_in[1];
  const float* W = (const float*)d_in[2];
  const float* a = (const float*)d_in[3];
  float* out = (float*)d_out;

  char* ws = (char*)d_ws;
  size_t off = 0;
  auto alloc = [&](size_t bytes) -> void* {
    void* p = ws + off;
    off += (bytes + 255) & ~(size_t)255;
    return p;
  };
  float* w123 = (float*)alloc(3 * DINq * sizeof(float));
  float* WT = (float*)alloc((size_t)DINq * DINq * sizeof(float));
  float* tA = (float*)alloc((size_t)Bq * Nq * sizeof(float));
  float* siA = (float*)alloc((size_t)Bq * Nq * sizeof(float));
  float* sbA = (float*)alloc((size_t)Bq * Nq * sizeof(float));
  float* sjvA = (float*)alloc((size_t)Bq * Nq * sizeof(float));
  float* sjp = (float*)alloc((size_t)8 * Bq * Nq * sizeof(float));
  float* h = (float*)alloc((size_t)Bq * Nq * DINq * sizeof(float));
  unsigned short* Xhi = (unsigned short*)alloc((size_t)Nq * Nq * 2);
  unsigned short* Xlo = (unsigned short*)alloc((size_t)Nq * Nq * 2);
  unsigned short* Mb = (unsigned short*)alloc((size_t)Nq * Nq * 2);

  k_prep<<<dim3(1), dim3(256), 0, stream>>>(W, a, w123);
  k_transposeW<<<dim3(DINq), dim3(DINq), 0, stream>>>(W, WT);
  k_tsisb<<<dim3(Nq / 64, Bq), dim3(256), 0, stream>>>(x, w123, tA, siA, sbA);
  k_hX<<<dim3(Nq / 64, 2, Bq), dim3(256), 0, stream>>>(x, WT, tA, h, Xhi, Xlo);
  k_mask<<<dim3(Nq * Nq / (256 * 8)), dim3(256), 0, stream>>>(adj, Mb);
  k_gemm<<<dim3(16, 16, 2), dim3(256), 0, stream>>>(Mb, Xhi, Xlo, h, sjp);
  k_sjsum<<<dim3(Bq * Nq / 256), dim3(256), 0, stream>>>(sbA, sjp, sjvA);
  k_softmax<<<dim3(Nq, Bq), dim3(256), 0, stream>>>(adj, siA, sjvA, out);
}

// Round 3
// 150.465 us; speedup vs baseline: 1.1160x; 1.0833x over previous
//
#include <hip/hip_runtime.h>
#include <hip/hip_bf16.h>
#include <math.h>

#define Bq   8
#define DINq 256
#define Nq   2048

typedef __attribute__((ext_vector_type(8))) short bf16x8v;
typedef __attribute__((ext_vector_type(4))) float f32x4v;

__device__ __forceinline__ unsigned short f2bf(float f) {
  union { float f; unsigned u; } v; v.f = f;
  unsigned r = v.u + 0x7fffu + ((v.u >> 16) & 1u);
  return (unsigned short)(r >> 16);
}
__device__ __forceinline__ float bf2f(unsigned short h) {
  union { unsigned u; float f; } v; v.u = ((unsigned)h) << 16;
  return v.f;
}

__device__ __forceinline__ void gld_lds16(const void* g, void* l) {
  __builtin_amdgcn_global_load_lds(
      (const __attribute__((address_space(1))) unsigned int*)g,
      (__attribute__((address_space(3))) unsigned int*)l, 16, 0, 0);
}

// ---- w123[k] = (W^T a1)[k], (W^T a2)[k], (W^T a3)[k] ----
__global__ void k_prep(const float* __restrict__ W, const float* __restrict__ a,
                       float* __restrict__ w123) {
  int k = threadIdx.x;
  float s1 = 0.f, s2 = 0.f, s3 = 0.f;
  for (int d = 0; d < DINq; ++d) {
    float w = W[d * DINq + k];
    s1 += w * a[d];
    s2 += w * a[DINq + d];
    s3 += w * a[2 * DINq + d];
  }
  w123[k] = s1; w123[DINq + k] = s2; w123[2 * DINq + k] = s3;
}

// ---- WT[k][d] = W[d][k] ----
__global__ void k_transposeW(const float* __restrict__ W, float* __restrict__ WT) {
  int d = blockIdx.x, k = threadIdx.x;
  WT[(size_t)k * DINq + d] = W[(size_t)d * DINq + k];
}

// ---- t, si, sb per (b,i): dot of x column with w123 vectors ----
__global__ void k_tsisb(const float* __restrict__ x, const float* __restrict__ w123,
                        float* __restrict__ tA, float* __restrict__ siA,
                        float* __restrict__ sbA) {
  int b = blockIdx.y;
  int il = threadIdx.x & 63;
  int i = blockIdx.x * 64 + il;
  int ks = (threadIdx.x >> 6) * 64;
  float a1 = 0.f, a2 = 0.f, a3 = 0.f;
  for (int k = ks; k < ks + 64; ++k) {
    float xv = x[((size_t)b * DINq + k) * Nq + i];
    a1 += xv * w123[k];
    a2 += xv * w123[DINq + k];
    a3 += xv * w123[2 * DINq + k];
  }
  __shared__ float r1[256], r2[256], r3[256];
  r1[threadIdx.x] = a1; r2[threadIdx.x] = a2; r3[threadIdx.x] = a3;
  __syncthreads();
  if (threadIdx.x < 64) {
    int l = threadIdx.x;
    float v1 = r1[l] + r1[64 + l] + r1[128 + l] + r1[192 + l];
    float v2 = r2[l] + r2[64 + l] + r2[128 + l] + r2[192 + l];
    float v3 = r3[l] + r3[64 + l] + r3[128 + l] + r3[192 + l];
    int ii = blockIdx.x * 64 + l;
    siA[(size_t)b * Nq + ii] = v1;
    sbA[(size_t)b * Nq + ii] = v2;
    tA[(size_t)b * Nq + ii] = v3;
  }
}

// ---- h[b,i,d] (fp32) and X^T[(b,d)][i] = t[b,i]*h[b,i,d] split hi/lo bf16 ----
__global__ void k_hX(const float* __restrict__ x, const float* __restrict__ WT,
                     const float* __restrict__ tA, float* __restrict__ h,
                     unsigned short* __restrict__ Xhi, unsigned short* __restrict__ Xlo) {
  __shared__ float xs[64][64];
  __shared__ float ws[64][128];
  const int tid = threadIdx.x;
  const int iq = tid & 15;      // 4 i's each
  const int dg = tid >> 4;      // 16 groups of 8 d's
  const int i0 = blockIdx.x * 64;
  const int dh = blockIdx.y;    // d half: 0 or 1
  const int b = blockIdx.z;

  float acc[4][8];
#pragma unroll
  for (int aa = 0; aa < 4; ++aa)
#pragma unroll
    for (int cc = 0; cc < 8; ++cc) acc[aa][cc] = 0.f;

  for (int kc = 0; kc < 4; ++kc) {
#pragma unroll
    for (int n = 0; n < 16; ++n) {
      int idx = n * 256 + tid;
      int kk = idx >> 6, ii = idx & 63;
      xs[kk][ii] = x[((size_t)b * DINq + kc * 64 + kk) * Nq + i0 + ii];
    }
#pragma unroll
    for (int n = 0; n < 8; ++n) {
      int idx = n * 256 + tid;
      int kk = idx >> 5, c4 = (idx & 31) * 4;
      *(f32x4v*)&ws[kk][c4] =
          *(const f32x4v*)&WT[(size_t)(kc * 64 + kk) * DINq + dh * 128 + c4];
    }
    __syncthreads();
#pragma unroll 4
    for (int kk = 0; kk < 64; ++kk) {
      f32x4v xv = *(const f32x4v*)&xs[kk][iq * 4];
      f32x4v w0 = *(const f32x4v*)&ws[kk][dg * 8];
      f32x4v w1 = *(const f32x4v*)&ws[kk][dg * 8 + 4];
#pragma unroll
      for (int aa = 0; aa < 4; ++aa) {
#pragma unroll
        for (int cc = 0; cc < 4; ++cc) {
          acc[aa][cc]     += xv[aa] * w0[cc];
          acc[aa][cc + 4] += xv[aa] * w1[cc];
        }
      }
    }
    __syncthreads();
  }

  const int ib = i0 + iq * 4;
  float tv[4];
#pragma unroll
  for (int aa = 0; aa < 4; ++aa) tv[aa] = tA[(size_t)b * Nq + ib + aa];

#pragma unroll
  for (int aa = 0; aa < 4; ++aa) {
    size_t hoff = ((size_t)b * Nq + ib + aa) * DINq + dh * 128 + dg * 8;
    f32x4v h0, h1;
#pragma unroll
    for (int cc = 0; cc < 4; ++cc) { h0[cc] = acc[aa][cc]; h1[cc] = acc[aa][cc + 4]; }
    *(f32x4v*)&h[hoff] = h0;
    *(f32x4v*)&h[hoff + 4] = h1;
  }
#pragma unroll
  for (int cc = 0; cc < 8; ++cc) {
    int d = dh * 128 + dg * 8 + cc;
    unsigned short hv[4], lv[4];
#pragma unroll
    for (int aa = 0; aa < 4; ++aa) {
      float Xv = tv[aa] * acc[aa][cc];
      unsigned short hs = f2bf(Xv);
      hv[aa] = hs;
      lv[aa] = f2bf(Xv - bf2f(hs));
    }
    size_t xoff = ((size_t)b * DINq + d) * Nq + ib;
    *(ushort4*)&Xhi[xoff] = make_ushort4(hv[0], hv[1], hv[2], hv[3]);
    *(ushort4*)&Xlo[xoff] = make_ushort4(lv[0], lv[1], lv[2], lv[3]);
  }
}

// ---- Mb[i][j] = (adj!=0 && i!=j) ? 1.0bf16 : 0 ----
__global__ void k_mask(const int* __restrict__ adj, unsigned short* __restrict__ Mb) {
  size_t idx = ((size_t)blockIdx.x * 256 + threadIdx.x) * 8;
  int i = (int)(idx >> 11);
  int j0 = (int)(idx & (Nq - 1));
  const int4* ap = (const int4*)&adj[idx];
  int4 a0 = ap[0], a1 = ap[1];
  int av[8] = {a0.x, a0.y, a0.z, a0.w, a1.x, a1.y, a1.z, a1.w};
  unsigned short v[8];
#pragma unroll
  for (int q = 0; q < 8; ++q)
    v[q] = (av[q] != 0 && (j0 + q) != i) ? (unsigned short)0x3F80 : (unsigned short)0;
  ushort4* mp = (ushort4*)&Mb[idx];
  mp[0] = make_ushort4(v[0], v[1], v[2], v[3]);
  mp[1] = make_ushort4(v[4], v[5], v[6], v[7]);
}

// ---- z-split GEMM, counted-vmcnt triple-buffer BK=32, swizzled LDS ----
// For z in {hi,lo}: Gz = Mb @ Xz^T (128x128 tile), fused epilogue reduces
// sjv partial = sum_d h[b,i,d]*Gz[i,(b,d)] into sjp slices.
__global__ __launch_bounds__(256, 2) void k_gemm(const unsigned short* __restrict__ Mb,
                                                 const unsigned short* __restrict__ Xhi,
                                                 const unsigned short* __restrict__ Xlo,
                                                 const float* __restrict__ h,
                                                 float* __restrict__ sjp) {
  // 3 buffers x (128 rows x 32 k) bf16, 8 KB each matrix = 48 KB total.
  __shared__ __align__(16) unsigned short As[3][128 * 32];
  __shared__ __align__(16) unsigned short Bs[3][128 * 32];
  const int tid = threadIdx.x;
  const int lane = tid & 63;
  const int wave = tid >> 6;
  const int wr = wave >> 1, wc = wave & 1;
  const int i0 = blockIdx.y * 128, c0 = blockIdx.x * 128;
  const int z = blockIdx.z;
  const unsigned short* __restrict__ Xp = z ? Xlo : Xhi;
  const int r15 = lane & 15, kg = lane >> 4;
  // swizzled k-byte within a 64B row: chunk kg XOR (row&3); row&3 == r15&3
  const int kb = (kg * 16) ^ ((r15 & 3) << 4);

  f32x4v acc[4][4];
#pragma unroll
  for (int m = 0; m < 4; ++m)
#pragma unroll
    for (int n = 0; n < 4; ++n) acc[m][n] = (f32x4v)0.f;

  // Stage K-tile t (k = [t*32, t*32+32)) into buffer `buf`.
  // Linear LDS dest (chunk c at byte c*16); global src pre-swizzled so that
  // phys chunk q of row holds logical k-chunk (q ^ (row&3)).
  auto STAGE = [&](int buf, int t) {
    const int k0 = t * 32;
#pragma unroll
    for (int l = 0; l < 2; ++l) {
      const int c = tid + 256 * l;
      const int row = c >> 2, q = c & 3;
      const int kc = 8 * (q ^ (row & 3));
      gld_lds16(&Mb[(size_t)(i0 + row) * Nq + k0 + kc], &As[buf][c * 8]);
      gld_lds16(&Xp[(size_t)(c0 + row) * Nq + k0 + kc], &Bs[buf][c * 8]);
    }
  };

  constexpr int NT = Nq / 32;  // 64
  STAGE(0, 0);
  STAGE(1, 1);
  int cb = 0, sb = 2;
  for (int t = 0; t < NT; ++t) {
    // Counted wait: drain tile t's 4 loads; tile t+1's stay in flight.
    if (t < NT - 2) {
      asm volatile("s_waitcnt vmcnt(4)" ::: "memory");
    } else {
      asm volatile("s_waitcnt vmcnt(0)" ::: "memory");
    }
    __builtin_amdgcn_sched_barrier(0);
    __builtin_amdgcn_s_barrier();
    __builtin_amdgcn_sched_barrier(0);
    if (t + 2 < NT) STAGE(sb, t + 2);  // overwrites buffer freed at iter t-1

    const char* Ab = (const char*)&As[cb][0];
    const char* Bb = (const char*)&Bs[cb][0];
    bf16x8v af[4], bf[4];
#pragma unroll
    for (int m = 0; m < 4; ++m)
      af[m] = *(const bf16x8v*)(Ab + (wr * 64 + m * 16 + r15) * 64 + kb);
#pragma unroll
    for (int n = 0; n < 4; ++n)
      bf[n] = *(const bf16x8v*)(Bb + (wc * 64 + n * 16 + r15) * 64 + kb);
    __builtin_amdgcn_s_setprio(1);
#pragma unroll
    for (int m = 0; m < 4; ++m)
#pragma unroll
      for (int n = 0; n < 4; ++n)
        acc[m][n] = __builtin_amdgcn_mfma_f32_16x16x32_bf16(af[m], bf[n], acc[m][n], 0, 0, 0);
    __builtin_amdgcn_s_setprio(0);
    cb = (cb == 2) ? 0 : cb + 1;
    sb = (sb == 2) ? 0 : sb + 1;
  }

  // Fused epilogue: partial[b, i] = sum over this block's 64-col (per wave) slice
  // of h[b, i, d] * acc. Cols c = c0 + wc*64 + n*16 + ce -> b = c>>8, d = c&255.
  const int b = c0 >> 8;
  const int d0 = (c0 & 255) + wc * 64;
  const int re = (lane >> 4) * 4, ce = lane & 15;
  float s[4][4];
#pragma unroll
  for (int m = 0; m < 4; ++m)
#pragma unroll
    for (int r = 0; r < 4; ++r) s[m][r] = 0.f;
#pragma unroll
  for (int m = 0; m < 4; ++m) {
#pragma unroll
    for (int n = 0; n < 4; ++n) {
#pragma unroll
      for (int r = 0; r < 4; ++r) {
        float hv = h[((size_t)b * Nq + i0 + wr * 64 + m * 16 + re + r) * DINq + d0 + n * 16 + ce];
        s[m][r] += acc[m][n][r] * hv;
      }
    }
  }
#pragma unroll
  for (int o = 1; o < 16; o <<= 1) {
#pragma unroll
    for (int m = 0; m < 4; ++m)
#pragma unroll
      for (int r = 0; r < 4; ++r) s[m][r] += __shfl_xor(s[m][r], o, 64);
  }
  if (ce == 0) {
    const int slice = z * 4 + (blockIdx.x & 1) * 2 + wc;
    float* sp = sjp + ((size_t)slice * Bq + b) * Nq;
#pragma unroll
    for (int m = 0; m < 4; ++m)
#pragma unroll
      for (int r = 0; r < 4; ++r)
        sp[i0 + wr * 64 + m * 16 + re + r] = s[m][r];
  }
}

// ---- sjv[b,i] = sb[b,i] + sum of 8 partial slices ----
__global__ void k_sjsum(const float* __restrict__ sbA, const float* __restrict__ sjp,
                        float* __restrict__ sjvA) {
  int idx = blockIdx.x * 256 + threadIdx.x;
  float s = sbA[idx];
#pragma unroll
  for (int sl = 0; sl < 8; ++sl) s += sjp[(size_t)sl * Bq * Nq + idx];
  sjvA[idx] = s;
}

// ---- out[b,i,:] = softmax_j( mask(adj, lrelu(si[b,i] + sjv[b,j])) ) ----
__global__ void k_softmax(const int* __restrict__ adj, const float* __restrict__ siA,
                          const float* __restrict__ sjvA, float* __restrict__ out) {
  const int b = blockIdx.y, i = blockIdx.x, tid = threadIdx.x;
  const float siv = siA[(size_t)b * Nq + i];
  const int* arow = adj + (size_t)i * Nq;
  const float* sjb = sjvA + (size_t)b * Nq;
  float sc[8];
  float mx = -3.0e38f;
#pragma unroll
  for (int s = 0; s < 8; ++s) {
    int j = s * 256 + tid;
    float v = siv + sjb[j];
    v = v > 0.f ? v : 0.2f * v;
    v = (arow[j] != 0) ? v : -9.0e15f;
    sc[s] = v;
    mx = fmaxf(mx, v);
  }
#pragma unroll
  for (int o = 32; o >= 1; o >>= 1) mx = fmaxf(mx, __shfl_xor(mx, o, 64));
  __shared__ float redm[4], reds[4];
  const int wave = tid >> 6, lane = tid & 63;
  if (lane == 0) redm[wave] = mx;
  __syncthreads();
  mx = fmaxf(fmaxf(redm[0], redm[1]), fmaxf(redm[2], redm[3]));
  float sum = 0.f, ex[8];
#pragma unroll
  for (int s = 0; s < 8; ++s) { ex[s] = expf(sc[s] - mx); sum += ex[s]; }
#pragma unroll
  for (int o = 32; o >= 1; o >>= 1) sum += __shfl_xor(sum, o, 64);
  if (lane == 0) reds[wave] = sum;
  __syncthreads();
  sum = reds[0] + reds[1] + reds[2] + reds[3];
  float inv = 1.f / sum;
  float* orow = out + ((size_t)b * Nq + i) * Nq;
#pragma unroll
  for (int s = 0; s < 8; ++s) orow[s * 256 + tid] = ex[s] * inv;
}

extern "C" void kernel_launch(void* const* d_in, const int* in_sizes, int n_in,
                              void* d_out, int out_size, void* d_ws, size_t ws_size,
                              hipStream_t stream) {
  const float* x = (const float*)d_in[0];
  const int* adj = (const int*)d_in[1];
  const float* W = (const float*)d_in[2];
  const float* a = (const float*)d_in[3];
  float* out = (float*)d_out;

  char* ws = (char*)d_ws;
  size_t off = 0;
  auto alloc = [&](size_t bytes) -> void* {
    void* p = ws + off;
    off += (bytes + 255) & ~(size_t)255;
    return p;
  };
  float* w123 = (float*)alloc(3 * DINq * sizeof(float));
  float* WT = (float*)alloc((size_t)DINq * DINq * sizeof(float));
  float* tA = (float*)alloc((size_t)Bq * Nq * sizeof(float));
  float* siA = (float*)alloc((size_t)Bq * Nq * sizeof(float));
  float* sbA = (float*)alloc((size_t)Bq * Nq * sizeof(float));
  float* sjvA = (float*)alloc((size_t)Bq * Nq * sizeof(float));
  float* sjp = (float*)alloc((size_t)8 * Bq * Nq * sizeof(float));
  float* h = (float*)alloc((size_t)Bq * Nq * DINq * sizeof(float));
  unsigned short* Xhi = (unsigned short*)alloc((size_t)Nq * Nq * 2);
  unsigned short* Xlo = (unsigned short*)alloc((size_t)Nq * Nq * 2);
  unsigned short* Mb = (unsigned short*)alloc((size_t)Nq * Nq * 2);

  k_prep<<<dim3(1), dim3(256), 0, stream>>>(W, a, w123);
  k_transposeW<<<dim3(DINq), dim3(DINq), 0, stream>>>(W, WT);
  k_tsisb<<<dim3(Nq / 64, Bq), dim3(256), 0, stream>>>(x, w123, tA, siA, sbA);
  k_hX<<<dim3(Nq / 64, 2, Bq), dim3(256), 0, stream>>>(x, WT, tA, h, Xhi, Xlo);
  k_mask<<<dim3(Nq * Nq / (256 * 8)), dim3(256), 0, stream>>>(adj, Mb);
  k_gemm<<<dim3(16, 16, 2), dim3(256), 0, stream>>>(Mb, Xhi, Xlo, h, sjp);
  k_sjsum<<<dim3(Bq * Nq / 256), dim3(256), 0, stream>>>(sbA, sjp, sjvA);
  k_softmax<<<dim3(Nq, Bq), dim3(256), 0, stream>>>(adj, siA, sjvA, out);
}